// Round 6
// baseline (411.860 us; speedup 1.0000x reference)
//
#include <hip/hip_runtime.h>

typedef __attribute__((ext_vector_type(8))) short bf16x8;
typedef __attribute__((ext_vector_type(4))) float f32x4;

#define WS_QKV   0          // 384 KiB: qkv frags (48 rt * 8 ks * 1024B), q-rows prescaled
#define WS_PROJ  393216     // 128 KiB: proj frags (16 rt * 8 ks * 1024B)
#define WS_MASKP 524288     // 1 MiB: maskp[64][64][64] f32 * log2e (j>=49 -> -1e30)
#define WS_BIAS  1572864    // 128 KiB: bias_hm[8][64][64] f32 * log2e
#define WS_QB    1703936    // 3 KiB: qkvb_s[768] (q part prescaled by scale*log2e)

#define QSCALE 0.17677669529663687f   // 1/sqrt(32)
#define LOG2E  1.4426950408889634f

__device__ __forceinline__ unsigned short f2bf(float f) {
  unsigned u = __builtin_bit_cast(unsigned, f);
  u += 0x7FFFu + ((u >> 16) & 1u);
  return (unsigned short)(u >> 16);
}

__device__ __forceinline__ unsigned long long pack4bf(f32x4 v) {
  unsigned long long r0 = f2bf(v[0]);
  unsigned long long r1 = f2bf(v[1]);
  unsigned long long r2 = f2bf(v[2]);
  unsigned long long r3 = f2bf(v[3]);
  return r0 | (r1 << 16) | (r2 << 32) | (r3 << 48);
}

// frag(rt,ks): lane l holds W[16*rt + (l&15)][32*ks + 8*(l>>4) + i], i=0..7 (bf16)
__global__ void prep_weights(const float* __restrict__ qkv_w,
                             const float* __restrict__ proj_w,
                             unsigned char* __restrict__ ws) {
  int g = blockIdx.x;   // 0..511
  int l = threadIdx.x;  // 0..63
  int lr = l & 15, lg = l >> 4;
  const float* src;
  float sc = 1.f;
  if (g < 384) {
    int rt = g >> 3, ks = g & 7;
    src = qkv_w + (size_t)(16 * rt + lr) * 256 + 32 * ks + 8 * lg;
    if (rt < 16) sc = QSCALE * LOG2E;  // fold scale and log2e into q rows
  } else {
    int p = g - 384;
    int rt = p >> 3, ks = p & 7;
    src = proj_w + (size_t)(16 * rt + lr) * 256 + 32 * ks + 8 * lg;
  }
  f32x4 a = *(const f32x4*)(src)*sc;
  f32x4 b = *(const f32x4*)(src + 4) * sc;
  unsigned long long* dst = (unsigned long long*)(ws + (size_t)g * 1024 + l * 16);
  dst[0] = pack4bf(a);
  dst[1] = pack4bf(b);
}

__global__ void prep_aux(const float* __restrict__ mask,
                         const float* __restrict__ bias_table,
                         const float* __restrict__ qkv_b,
                         unsigned char* __restrict__ ws) {
  int bid = blockIdx.x, tid = threadIdx.x;
  if (bid < 64) {  // maskp[w][64][64] * log2e
    float* dst = (float*)(ws + WS_MASKP) + (size_t)bid * 4096;
    for (int it = 0; it < 16; ++it) {
      int idx = it * 256 + tid;
      int m = idx >> 6, j = idx & 63;
      float v;
      if (j >= 49) v = -1e30f;
      else if (m >= 49) v = 0.f;
      else v = mask[((size_t)bid * 49 + m) * 49 + j] * LOG2E;
      dst[idx] = v;
    }
  } else if (bid < 72) {  // bias_hm[h][64][64] * log2e
    int h = bid - 64;
    float* dst = (float*)(ws + WS_BIAS) + (size_t)h * 4096;
    for (int it = 0; it < 16; ++it) {
      int idx = it * 256 + tid;
      int m = idx >> 6, j = idx & 63;
      float v = 0.f;
      if (m < 49 && j < 49) {
        int rm = m / 7, cm = m % 7, rj = j / 7, cj = j % 7;
        int rpi = (rm - rj + 6) * 13 + (cm - cj + 6);
        v = bias_table[rpi * 8 + h] * LOG2E;
      }
      dst[idx] = v;
    }
  } else {  // qkv bias: q part prescaled
    float* dst = (float*)(ws + WS_QB);
    for (int i = tid; i < 768; i += 256)
      dst[i] = qkv_b[i] * (i < 256 ? QSCALE * LOG2E : 1.f);
  }
}

// One block = one window, 16 waves (1024 thr). Wave pair (h = wv>>1, s = wv&1):
// wave s owns m-rows [32s, 32s+32) of head h's attention.
// LDS 122 KiB, single block; __launch_bounds__(1024,4) caps total regs at 128
// -> 16 waves/CU (4/SIMD).
//  [0,32K)        xs: bf16 x[64][256], byte(r,c) = r*512 + ((2c)^((r&7)<<4));
//                 reused as ao[m][256ch] after PV (same swizzle on (m&7))
//  per head h:    bufQ = 32768 + h*9216  (q: [m][32d] stride 72; later vT:
//                   [d][64tok] stride 128, byte = d*128 + ((2tok)^((d&7)<<4)))
//                 bufK = bufQ + 4608     (k: [m][32d] stride 72)
//  per wave:      bufP = 106496 + wv*1152  ([16 m][32 j] stride 72)
__global__ __launch_bounds__(1024, 4)
void winattn_main(const float* __restrict__ x,
                  const unsigned char* __restrict__ ws,
                  const float* __restrict__ proj_b,
                  float* __restrict__ out) {
  __shared__ __align__(16) unsigned char lds[124928];
  const int tid = threadIdx.x;
  const int wv = tid >> 6, ln = tid & 63;
  const int lr = ln & 15, lg = ln >> 4;
  const int b = blockIdx.x;
  const int w = b & 63;
  const int h = wv >> 1, s = wv & 1;
  const float* maskp = (const float*)(ws + WS_MASKP) + (size_t)w * 4096;
  const float* biasp = (const float*)(ws + WS_BIAS) + (size_t)h * 4096;
  const float* qbs = (const float*)(ws + WS_QB);
  unsigned char* bufQ = lds + 32768 + h * 9216;  // q, then vT
  unsigned char* bufK = bufQ + 4608;
  unsigned char* bufP = lds + 106496 + wv * 1152;

  // ---- Phase 1: stage x -> xs (bf16, swizzled), rows >= 49 zeroed
  {
    const int r = tid >> 4;          // 0..63
    const int c0 = (tid & 15) * 4;   // 0..60
    const float* xrow = x + ((size_t)b * 49 + r) * 256;
    unsigned char* row = lds + r * 512;
    const int swz = (r & 7) << 4;
#pragma unroll
    for (int u = 0; u < 4; ++u) {
      int c = c0 + 64 * u;
      f32x4 v = {0.f, 0.f, 0.f, 0.f};
      if (r < 49) v = *(const f32x4*)(xrow + c);
      *(unsigned long long*)(row + ((2 * c) ^ swz)) = pack4bf(v);
    }
  }
  __syncthreads();

  // ---- Phase B: QKV GEMMs for head h, t-tiles split across the wave pair.
  bf16x8 qf[2], kf[4];
#pragma unroll
  for (int pp = 0; pp < 3; ++pp) {  // 0=q, 1=k, 2=v
    const int rtb = (pp == 0 ? 0 : (pp == 1 ? 16 : 32)) + 2 * h;
    bf16x8 af0[8], af1[8];
#pragma unroll
    for (int ks = 0; ks < 8; ++ks) {
      af0[ks] = *(const bf16x8*)(ws + (size_t)(rtb * 8 + ks) * 1024 + ln * 16);
      af1[ks] = *(const bf16x8*)(ws + (size_t)((rtb + 1) * 8 + ks) * 1024 + ln * 16);
    }
    f32x4 c0, c1;
    if (pp < 2) {
      c0 = *(const f32x4*)(qbs + pp * 256 + 32 * h + 4 * lg);
      c1 = *(const f32x4*)(qbs + pp * 256 + 32 * h + 16 + 4 * lg);
    } else {
      float vb0 = qbs[512 + 32 * h + lr];
      float vb1 = qbs[512 + 32 * h + 16 + lr];
      c0 = {vb0, vb0, vb0, vb0};
      c1 = {vb1, vb1, vb1, vb1};
    }
#pragma unroll
    for (int ti = 0; ti < 2; ++ti) {
      const int t = 2 * s + ti;
      const int row = 16 * t + lr;
      const unsigned char* rp = lds + row * 512;
      const int swz = (row & 7) << 4;
      bf16x8 xfr[8];
#pragma unroll
      for (int ks = 0; ks < 8; ++ks)
        xfr[ks] = *(const bf16x8*)(rp + ((64 * ks + 16 * lg) ^ swz));
      f32x4 a0 = c0, a1 = c1;
      if (pp < 2) {
        // D[ch][tok]: col = tok = 16t+lr, rows = ch
#pragma unroll
        for (int ks = 0; ks < 8; ++ks) {
          a0 = __builtin_amdgcn_mfma_f32_16x16x32_bf16(af0[ks], xfr[ks], a0, 0, 0, 0);
          a1 = __builtin_amdgcn_mfma_f32_16x16x32_bf16(af1[ks], xfr[ks], a1, 0, 0, 0);
        }
        unsigned char* dst = (pp == 0 ? bufQ : bufK);
        *(unsigned long long*)(dst + row * 72 + 8 * lg) = pack4bf(a0);
        *(unsigned long long*)(dst + row * 72 + 32 + 8 * lg) = pack4bf(a1);
      } else {
        // D[tok][d]: col = d, rows = tok -> vT[d][tok] (into bufQ, q consumed)
#pragma unroll
        for (int ks = 0; ks < 8; ++ks) {
          a0 = __builtin_amdgcn_mfma_f32_16x16x32_bf16(xfr[ks], af0[ks], a0, 0, 0, 0);
          a1 = __builtin_amdgcn_mfma_f32_16x16x32_bf16(xfr[ks], af1[ks], a1, 0, 0, 0);
        }
        const int tb = 32 * t + 8 * lg;
        *(unsigned long long*)(bufQ + lr * 128 + (tb ^ ((lr & 7) << 4))) = pack4bf(a0);
        *(unsigned long long*)(bufQ + (16 + lr) * 128 + (tb ^ ((lr & 7) << 4))) = pack4bf(a1);
      }
    }
    __syncthreads();
    if (pp == 0) {
#pragma unroll
      for (int i = 0; i < 2; ++i)
        qf[i] = *(const bf16x8*)(bufQ + (lr + 32 * s + 16 * i) * 72 + 16 * lg);
    } else if (pp == 1) {
#pragma unroll
      for (int t = 0; t < 4; ++t)
        kf[t] = *(const bf16x8*)(bufK + (lr + 16 * t) * 72 + 16 * lg);
    }
  }
  // (pp-loop's final __syncthreads guarantees vT staged before PV reads)

  // ---- Phase C: S^T = K Q^T (C-init = mask+bias), exp2 softmax (no max-sub:
  //      logits bounded, masked cols -> -1e30 -> 0), online over j-halves.
  float sm[2] = {0.f, 0.f};
  f32x4 oacc[2][2];
#pragma unroll
  for (int dt = 0; dt < 2; ++dt)
#pragma unroll
    for (int i = 0; i < 2; ++i) oacc[dt][i] = {0.f, 0.f, 0.f, 0.f};

#pragma unroll
  for (int jh = 0; jh < 2; ++jh) {
    f32x4 s2[2][2];
#pragma unroll
    for (int jt2 = 0; jt2 < 2; ++jt2) {
      const int jt = 2 * jh + jt2;
#pragma unroll
      for (int i = 0; i < 2; ++i) {
        const int m = lr + 32 * s + 16 * i;
        f32x4 mk = *(const f32x4*)(maskp + m * 64 + 16 * jt + 4 * lg) +
                   *(const f32x4*)(biasp + m * 64 + 16 * jt + 4 * lg);
        s2[jt2][i] = __builtin_amdgcn_mfma_f32_16x16x32_bf16(kf[jt], qf[i], mk, 0, 0, 0);
#pragma unroll
        for (int r2 = 0; r2 < 4; ++r2) {
          float e = __builtin_amdgcn_exp2f(s2[jt2][i][r2]);
          s2[jt2][i][r2] = e;
          sm[i] += e;
        }
      }
    }
    bf16x8 vf[2];
#pragma unroll
    for (int dt = 0; dt < 2; ++dt) {
      const int d = lr + 16 * dt;
      vf[dt] = *(const bf16x8*)(bufQ + d * 128 + ((64 * jh + 16 * lg) ^ ((d & 7) << 4)));
    }
#pragma unroll
    for (int i = 0; i < 2; ++i) {
#pragma unroll
      for (int jt2 = 0; jt2 < 2; ++jt2)
        *(unsigned long long*)(bufP + lr * 72 + 32 * jt2 + 8 * lg) = pack4bf(s2[jt2][i]);
      bf16x8 pf = *(const bf16x8*)(bufP + lr * 72 + 16 * lg);
#pragma unroll
      for (int dt = 0; dt < 2; ++dt)
        oacc[dt][i] = __builtin_amdgcn_mfma_f32_16x16x32_bf16(vf[dt], pf, oacc[dt][i], 0, 0, 0);
    }
  }
  float inv[2];
#pragma unroll
  for (int i = 0; i < 2; ++i) {
    float t = sm[i];
    t += __shfl_xor(t, 16);
    t += __shfl_xor(t, 32);
    inv[i] = 1.f / t;
  }

  __syncthreads();  // all waves done reading xs -> safe to overwrite with ao

  // ao[m][256] into xs region: head h owns bytes [64h, 64h+64) per row
#pragma unroll
  for (int dt = 0; dt < 2; ++dt)
#pragma unroll
    for (int i = 0; i < 2; ++i) {
      const int m = lr + 32 * s + 16 * i;
      *(unsigned long long*)(lds + m * 512 +
                             ((64 * h + 32 * dt + 8 * lg) ^ ((m & 7) << 4))) =
          pack4bf(oacc[dt][i] * inv[i]);
    }
  __syncthreads();

  // ---- Phase D: proj^T[o][m] = sum_c Wp[o][c] * ao[m][c]; wave = out-tile wv
  {
    const unsigned char* wsP = ws + WS_PROJ;
    const int mt = wv;
    bf16x8 af[8];
#pragma unroll
    for (int ks = 0; ks < 8; ++ks)
      af[ks] = *(const bf16x8*)(wsP + (size_t)(mt * 8 + ks) * 1024 + ln * 16);
    f32x4 pb = *(const f32x4*)(proj_b + 16 * mt + 4 * lg);
#pragma unroll
    for (int tt = 0; tt < 4; ++tt) {
      const int m = lr + 16 * tt;
      f32x4 acc = {0.f, 0.f, 0.f, 0.f};
#pragma unroll
      for (int ks = 0; ks < 8; ++ks) {
        bf16x8 aof = *(const bf16x8*)(lds + m * 512 + ((64 * ks + 16 * lg) ^ ((m & 7) << 4)));
        acc = __builtin_amdgcn_mfma_f32_16x16x32_bf16(af[ks], aof, acc, 0, 0, 0);
      }
      if (m < 49) {
        acc += pb;
        *(f32x4*)(out + ((size_t)b * 49 + m) * 256 + 16 * mt + 4 * lg) = acc;
      }
    }
  }
}

extern "C" void kernel_launch(void* const* d_in, const int* in_sizes, int n_in,
                              void* d_out, int out_size, void* d_ws, size_t ws_size,
                              hipStream_t stream) {
  const float* x = (const float*)d_in[0];
  const float* mask = (const float*)d_in[1];
  const float* qkv_w = (const float*)d_in[2];
  const float* qkv_b = (const float*)d_in[3];
  const float* proj_w = (const float*)d_in[4];
  const float* proj_b = (const float*)d_in[5];
  const float* bias_table = (const float*)d_in[6];
  unsigned char* ws = (unsigned char*)d_ws;
  float* out = (float*)d_out;

  prep_weights<<<512, 64, 0, stream>>>(qkv_w, proj_w, ws);
  prep_aux<<<73, 256, 0, stream>>>(mask, bias_table, qkv_b, ws);
  winattn_main<<<4096, 1024, 0, stream>>>(x, ws, proj_b, out);
}